// Round 5
// baseline (454.053 us; speedup 1.0000x reference)
//
#include <hip/hip_runtime.h>

// ---------------- problem constants ----------------
#define HID   2048
#define NHEAD 16
#define HD    128
#define SEQ   2048
#define BATCH 2
#define MROWS (BATCH*SEQ)        // 4096
#define NQKV  (3*HID)            // 6144
#define NQK   (2*HID)            // 4096 (dense Q|K buffer row stride)
#define INV_NORM 0.08838834764831845f
#define LOG2E    1.4426950408889634f
#define SCALE_L2 (INV_NORM*LOG2E)

typedef __attribute__((ext_vector_type(8)))  __bf16 bf16x8;
typedef __attribute__((ext_vector_type(4)))  float  f32x4;
typedef __attribute__((ext_vector_type(16))) float  f32x16;

typedef __attribute__((address_space(1))) void GV;
typedef __attribute__((address_space(3))) void LV;

__device__ __forceinline__ void async16(const void* g, void* l) {
  __builtin_amdgcn_global_load_lds((const GV*)g, (LV*)l, 16, 0, 0);
}

__device__ __forceinline__ unsigned short f2bf(float f) {
  unsigned u = __builtin_bit_cast(unsigned, f);
  u += 0x7FFFu + ((u >> 16) & 1u);       // RNE
  return (unsigned short)(u >> 16);
}

__device__ __forceinline__ unsigned pkbf(float a, float b) {
#if __has_builtin(__builtin_amdgcn_cvt_pk_bf16_f32)
  typedef __attribute__((ext_vector_type(2))) __bf16 bf16x2;
  bf16x2 r = __builtin_amdgcn_cvt_pk_bf16_f32(a, b);
  return __builtin_bit_cast(unsigned, r);
#else
  return (unsigned)f2bf(a) | ((unsigned)f2bf(b) << 16);
#endif
}

__device__ __forceinline__ void mfma16(f32x4& c, bf16x8 a, bf16x8 b) {
  c = __builtin_amdgcn_mfma_f32_16x16x32_bf16(a, b, c, 0, 0, 0);
}

// ---------------- fp32 -> bf16 cast: X + Wq + Wk + Wv + Wd in one launch ----------------
// dst regions are contiguous: Xb (NX4 float4-chunks) | Wq | Wk | Wv | Wd (NW4 each)
#define NX4 2097152   // 4096*2048/4 = 2^21
#define NW4 1048576   // 2048*2048/4 = 2^20
__global__ __launch_bounds__(256) void cvt_all_kernel(
    const float* __restrict__ X,  const float* __restrict__ W0,
    const float* __restrict__ W1, const float* __restrict__ W2,
    const float* __restrict__ W3, unsigned short* __restrict__ dst) {
  long c = (long)blockIdx.x * 256 + threadIdx.x;   // float4-chunk id
  const float* src;
  long off;
  if (c < NX4) { src = X; off = c; }
  else {
    long r = c - NX4;
    int t = (int)(r >> 20);
    off = r & (NW4 - 1);
    src = (t == 0) ? W0 : (t == 1) ? W1 : (t == 2) ? W2 : W3;
  }
  float4 v = ((const float4*)src)[off];
  ushort4 o;
  o.x = f2bf(v.x); o.y = f2bf(v.y); o.z = f2bf(v.z); o.w = f2bf(v.w);
  ((ushort4*)dst)[c] = o;
}

// ---------------- 128x128 NT GEMM core, BK=64, XOR-swizzled LDS ----------------
__device__ __forceinline__ void gemm_core(const unsigned short* __restrict__ A,
                                          const unsigned short* __restrict__ Bm,
                                          int K, int m0, int n0,
                                          unsigned short* As, unsigned short* Bs,
                                          f32x4 (&acc)[4][4]) {
  const int tid  = threadIdx.x;
  const int w    = tid >> 6;
  const int lane = tid & 63;
  const int l16  = lane & 15;
  const int quad = lane >> 4;
  const int wm   = (w & 1) * 64;
  const int wn   = (w >> 1) * 64;

  const f32x4 zero = {0.f, 0.f, 0.f, 0.f};
#pragma unroll
  for (int i = 0; i < 4; ++i)
#pragma unroll
    for (int j = 0; j < 4; ++j) acc[i][j] = zero;

  for (int k0 = 0; k0 < K; k0 += 64) {
    __syncthreads();
#pragma unroll
    for (int i = 0; i < 4; ++i) {
      int slot = i * 256 + w * 64 + lane;
      int r = slot >> 3;
      int c = (slot & 7) ^ (r & 7);
      async16(A  + (size_t)(m0 + r) * K + k0 + c * 8, (char*)As + (size_t)(i * 256 + w * 64) * 16);
      async16(Bm + (size_t)(n0 + r) * K + k0 + c * 8, (char*)Bs + (size_t)(i * 256 + w * 64) * 16);
    }
    __syncthreads();

#pragma unroll
    for (int kk = 0; kk < 2; ++kk) {
      bf16x8 af[4], bfp[4];
#pragma unroll
      for (int i = 0; i < 4; ++i) {
        int rr = wm + i * 16 + l16;
        af[i] = *(const bf16x8*)(As + ((rr * 8 + (((kk * 4 + quad)) ^ (rr & 7))) * 8));
      }
#pragma unroll
      for (int j = 0; j < 4; ++j) {
        int rr = wn + j * 16 + l16;
        bfp[j] = *(const bf16x8*)(Bs + ((rr * 8 + (((kk * 4 + quad)) ^ (rr & 7))) * 8));
      }
#pragma unroll
      for (int i = 0; i < 4; ++i)
#pragma unroll
        for (int j = 0; j < 4; ++j) mfma16(acc[i][j], af[i], bfp[j]);
    }
  }
}

// ---------------- GEMM 1: QKV projection ----------------
// Q/K blocks (n0 < 4096): bf16 + bias -> dense QK buffer (row stride 4096).
// V blocks (n0 >= 4096): bf16 + bias -> transposed Vt[bh][d][s] via LDS (no row-major V).
__global__ __launch_bounds__(256) void gemm_qkv_kernel(
    const unsigned short* __restrict__ Xb, const unsigned short* __restrict__ Wb,
    const float* __restrict__ bq, const float* __restrict__ bk,
    const float* __restrict__ bv, unsigned short* __restrict__ QK,
    unsigned short* __restrict__ Vt) {
  __shared__ __align__(16) char smem[32768];
  unsigned short* As = (unsigned short*)smem;
  unsigned short* Bs = (unsigned short*)(smem + 16384);
  unsigned short* T  = (unsigned short*)smem;   // 64x136 shorts = 17408 B, reused after core

  f32x4 acc[4][4];
  const int m0 = blockIdx.y * 128, n0 = blockIdx.x * 128;
  gemm_core(Xb, Wb, HID, m0, n0, As, Bs, acc);

  const int tid = threadIdx.x, w = tid >> 6, lane = tid & 63;
  const int l16 = lane & 15, quad = lane >> 4;
  const int wm = (w & 1) * 64, wn = (w >> 1) * 64;

  // biased bf16 values
  unsigned short cv[4][4][4];   // [i][j][r]
#pragma unroll
  for (int j = 0; j < 4; ++j) {
    int ng = n0 + wn + j * 16 + l16;
    float bias = (ng < HID) ? bq[ng] : (ng < 2 * HID ? bk[ng - HID] : bv[ng - 2 * HID]);
#pragma unroll
    for (int i = 0; i < 4; ++i)
#pragma unroll
      for (int r = 0; r < 4; ++r) cv[i][j][r] = f2bf(acc[i][j][r] + bias);
  }

  if (n0 < 2 * HID) {
    // Q/K: row-major into dense QK buffer
#pragma unroll
    for (int j = 0; j < 4; ++j) {
      int ng = n0 + wn + j * 16 + l16;
#pragma unroll
      for (int i = 0; i < 4; ++i)
#pragma unroll
        for (int r = 0; r < 4; ++r) {
          int mg = m0 + wm + i * 16 + quad * 4 + r;
          QK[(size_t)mg * NQK + ng] = cv[i][j][r];
        }
    }
  } else {
    // V: transpose via LDS, write Vt[bh][d][s] coalesced
    const int hh = (n0 - 2 * HID) >> 7;        // head
    const int b2 = m0 >> 11;                   // batch (uniform per block)
    const int s0l = m0 & 2047;
    unsigned short* Vdst = Vt + ((size_t)(b2 * NHEAD + hh) * HD) * SEQ;
#pragma unroll
    for (int p = 0; p < 2; ++p) {
      __syncthreads();   // prior smem use done
      if ((w >> 1) == p) {                     // waves with wn == 64*p hold d-cols [64p,64p+64)
#pragma unroll
        for (int j = 0; j < 4; ++j) {
          int cl = j * 16 + l16;               // d local within half
#pragma unroll
          for (int i = 0; i < 4; ++i) {
            ushort4 pk4;
            pk4.x = cv[i][j][0]; pk4.y = cv[i][j][1];
            pk4.z = cv[i][j][2]; pk4.w = cv[i][j][3];
            *(ushort4*)(T + cl * 136 + wm + i * 16 + quad * 4) = pk4;
          }
        }
      }
      __syncthreads();
#pragma unroll
      for (int ii = 0; ii < 4; ++ii) {
        int slot = ii * 256 + tid;             // 0..1023
        int d = slot >> 4, ch = slot & 15;
        uint4 val = *(const uint4*)(T + d * 136 + ch * 8);
        *(uint4*)(Vdst + (size_t)(p * 64 + d) * SEQ + s0l + ch * 8) = val;
      }
    }
  }
}

// ---------------- GEMM 2: out-proj + bias + residual, fp32 out ----------------
__global__ __launch_bounds__(256) void gemm_out_kernel(
    const unsigned short* __restrict__ Ctx, const unsigned short* __restrict__ Wdb,
    const float* __restrict__ bd, const float* __restrict__ Res,
    float* __restrict__ Out) {
  __shared__ __align__(16) char smem[32768];
  unsigned short* As = (unsigned short*)smem;
  unsigned short* Bs = (unsigned short*)(smem + 16384);
  f32x4 acc[4][4];
  const int m0 = blockIdx.y * 128, n0 = blockIdx.x * 128;
  gemm_core(Ctx, Wdb, HID, m0, n0, As, Bs, acc);

  const int tid = threadIdx.x, w = tid >> 6, lane = tid & 63;
  const int l16 = lane & 15, quad = lane >> 4;
  const int wm = (w & 1) * 64, wn = (w >> 1) * 64;
#pragma unroll
  for (int j = 0; j < 4; ++j) {
    int ng = n0 + wn + j * 16 + l16;
    float bias = bd[ng];
#pragma unroll
    for (int i = 0; i < 4; ++i)
#pragma unroll
      for (int r = 0; r < 4; ++r) {
        int mg = m0 + wm + i * 16 + quad * 4 + r;
        size_t off = (size_t)mg * HID + ng;
        Out[off] = acc[i][j][r] + bias + Res[off];
      }
  }
}

// ---------------- flash attention, 32x32 MFMA, S^T trick ----------------
// grid = (SEQ/128, BATCH*NHEAD); block 256 (4 waves, each 32 q-rows)
__global__ __launch_bounds__(256, 2) void attn_kernel(
    const unsigned short* __restrict__ QK, const unsigned short* __restrict__ Vt,
    const float* __restrict__ alibi, unsigned short* __restrict__ Ctx) {
  __shared__ __align__(16) char smem[51200];
  unsigned short* Ks  = (unsigned short*)smem;
  unsigned short* Vts = (unsigned short*)(smem + 16384);
  unsigned short* Ps  = (unsigned short*)(smem + 32768);
  unsigned short* Qs  = (unsigned short*)smem;          // alias: Q staging (32 KB)

  const int tid = threadIdx.x, w = tid >> 6, lane = tid & 63;
  const int l32 = lane & 31, h = lane >> 5;
  const int q0 = blockIdx.x * 128;
  const int bh = blockIdx.y, b = bh >> 4, hh = bh & 15;
  const size_t rowbase = (size_t)b * SEQ;
  const float* ali = alibi + (size_t)bh * SEQ;
  const unsigned short* Vbh = Vt + (size_t)bh * HD * SEQ;

  // ---- stage Q tile (128 x 128) once; hoist fragments to registers ----
  {
    const unsigned short* qbase = QK + (rowbase + q0) * NQK + hh * HD;
#pragma unroll
    for (int i = 0; i < 8; ++i) {
      int slot = i * 256 + w * 64 + lane;              // 0..2047
      int r = slot >> 4, c = (slot & 15) ^ (r & 15);
      async16(qbase + (size_t)r * NQK + c * 8, (char*)Qs + (size_t)(i * 256 + w * 64) * 16);
    }
  }
  __syncthreads();
  bf16x8 qf[8];
  {
    int qr = w * 32 + l32;
#pragma unroll
    for (int ks = 0; ks < 8; ++ks) {
      int c = (ks * 2 + h) ^ (qr & 15);
      qf[ks] = *(const bf16x8*)(Qs + (qr * 16 + c) * 8);
    }
  }

  f32x16 oacc[4];
  float l_acc = 0.f;
#pragma unroll
  for (int nb = 0; nb < 4; ++nb)
#pragma unroll
    for (int r = 0; r < 16; ++r) oacc[nb][r] = 0.f;

  __syncthreads();   // qf reads complete before K staging overwrites alias

  for (int kt = 0; kt < SEQ / 64; ++kt) {
    {
      const unsigned short* kbase = QK + (rowbase + kt * 64) * NQK + HID + hh * HD;
#pragma unroll
      for (int i = 0; i < 4; ++i) {
        int slot = i * 256 + w * 64 + lane;
        int r = slot >> 4, c = (slot & 15) ^ (r & 15);
        async16(kbase + (size_t)r * NQK + c * 8, (char*)Ks + (size_t)(i * 256 + w * 64) * 16);
      }
      const unsigned short* vbase = Vbh + kt * 64;
#pragma unroll
      for (int i = 0; i < 4; ++i) {
        int slot = i * 256 + w * 64 + lane;
        int r = slot >> 3, c = (slot & 7) ^ (r & 7);
        async16(vbase + (size_t)r * SEQ + c * 8, (char*)Vts + (size_t)(i * 256 + w * 64) * 16);
      }
    }
    __syncthreads();   // drain vmcnt -> tiles visible

    // S^T = K Q^T : D[m=key 64][n=q 32], K-depth 128
    f32x16 sacc[2];
#pragma unroll
    for (int mb = 0; mb < 2; ++mb)
#pragma unroll
      for (int r = 0; r < 16; ++r) sacc[mb][r] = 0.f;
#pragma unroll
    for (int ks = 0; ks < 8; ++ks) {
#pragma unroll
      for (int mb = 0; mb < 2; ++mb) {
        bf16x8 kf = *(const bf16x8*)(Ks + ((mb * 32 + l32) * 16 + ((ks * 2 + h) ^ (l32 & 15))) * 8);
        sacc[mb] = __builtin_amdgcn_mfma_f32_32x32x16_bf16(kf, qf[ks], sacc[mb], 0, 0, 0);
      }
    }

    // softmax (fixed-max): p = exp2(s*scale + a*log2e); per-lane q = l32+32w
    const float* alik = ali + kt * 64 + 4 * h;
    const int qrow = w * 32 + l32;
#pragma unroll
    for (int mb = 0; mb < 2; ++mb) {
#pragma unroll
      for (int g = 0; g < 4; ++g) {
        float4 av = *(const float4*)(alik + mb * 32 + g * 8);
        float p0 = __builtin_amdgcn_exp2f(sacc[mb][g * 4 + 0] * SCALE_L2 + av.x * LOG2E);
        float p1 = __builtin_amdgcn_exp2f(sacc[mb][g * 4 + 1] * SCALE_L2 + av.y * LOG2E);
        float p2 = __builtin_amdgcn_exp2f(sacc[mb][g * 4 + 2] * SCALE_L2 + av.z * LOG2E);
        float p3 = __builtin_amdgcn_exp2f(sacc[mb][g * 4 + 3] * SCALE_L2 + av.w * LOG2E);
        l_acc += (p0 + p1) + (p2 + p3);
        uint2 pk;
        pk.x = pkbf(p0, p1);
        pk.y = pkbf(p2, p3);
        *(uint2*)(Ps + qrow * 72 + mb * 32 + g * 8 + 4 * h) = pk;
      }
    }
    // Ps rows are wave-private: no barrier needed before PV

    // O += P V : D[m=q 32][n=d 128], K-depth 64
#pragma unroll
    for (int ks2 = 0; ks2 < 4; ++ks2) {
      bf16x8 pf = *(const bf16x8*)(Ps + qrow * 72 + ks2 * 16 + h * 8);
#pragma unroll
      for (int nb = 0; nb < 4; ++nb) {
        bf16x8 vf = *(const bf16x8*)(Vts + ((nb * 32 + l32) * 8 + ((ks2 * 2 + h) ^ (l32 & 7))) * 8);
        oacc[nb] = __builtin_amdgcn_mfma_f32_32x32x16_bf16(pf, vf, oacc[nb], 0, 0, 0);
      }
    }
    __syncthreads();   // PV reads done before next staging overwrite
  }

  // denominator: combine h-halves, then gather per C/D-row
  float lf = l_acc + __shfl_xor(l_acc, 32, 64);
  float rinv[16];
#pragma unroll
  for (int reg = 0; reg < 16; ++reg) {
    int row = (reg & 3) + 8 * (reg >> 2) + 4 * h;
    rinv[reg] = 1.0f / __shfl(lf, row, 64);
  }

#pragma unroll
  for (int nb = 0; nb < 4; ++nb)
#pragma unroll
    for (int reg = 0; reg < 16; ++reg) {
      int row = (reg & 3) + 8 * (reg >> 2) + 4 * h;
      size_t qg = rowbase + q0 + w * 32 + row;
      Ctx[qg * HID + hh * HD + nb * 32 + l32] = f2bf(oacc[nb][reg] * rinv[reg]);
    }
}

// ---------------- launch ----------------
extern "C" void kernel_launch(void* const* d_in, const int* in_sizes, int n_in,
                              void* d_out, int out_size, void* d_ws, size_t ws_size,
                              hipStream_t stream) {
  const float* hidden   = (const float*)d_in[0];
  const float* residual = (const float*)d_in[1];
  const float* alibi    = (const float*)d_in[2];
  const float* Wq = (const float*)d_in[3];
  const float* bq = (const float*)d_in[4];
  const float* Wk = (const float*)d_in[5];
  const float* bk = (const float*)d_in[6];
  const float* Wv = (const float*)d_in[7];
  const float* bv = (const float*)d_in[8];
  const float* Wd = (const float*)d_in[9];
  const float* bd = (const float*)d_in[10];
  float* out = (float*)d_out;

  unsigned short* Xb    = (unsigned short*)d_ws;                    // 4096*2048  (16.8 MB)
  unsigned short* Wqkvb = Xb + (size_t)MROWS * HID;                 // 6144*2048  (25.2 MB)
  unsigned short* Wdb   = Wqkvb + (size_t)NQKV * HID;               // 2048*2048  (8.4 MB)
  unsigned short* QKb   = Wdb + (size_t)HID * HID;                  // 4096*4096  (33.6 MB)
  unsigned short* Vtb   = QKb + (size_t)MROWS * NQK;                // 32*128*2048 (16.8 MB)
  unsigned short* Ctxb  = Vtb + (size_t)BATCH * NHEAD * HD * SEQ;   // 4096*2048  (16.8 MB)

  cvt_all_kernel<<<(NX4 + 4 * NW4) / 256, 256, 0, stream>>>(hidden, Wq, Wk, Wv, Wd, Xb);

  gemm_qkv_kernel<<<dim3(NQKV / 128, MROWS / 128), 256, 0, stream>>>(Xb, Wqkvb, bq, bk, bv, QKb, Vtb);
  attn_kernel<<<dim3(SEQ / 128, BATCH * NHEAD), 256, 0, stream>>>(QKb, Vtb, alibi, Ctxb);
  gemm_out_kernel<<<dim3(HID / 128, MROWS / 128), 256, 0, stream>>>(Ctxb, Wdb, bd, residual, out);
}